// Round 21
// baseline (112.273 us; speedup 1.0000x reference)
//
#include <hip/hip_runtime.h>

#define NB  2
#define NH  12
#define NQ  2048
#define NKV 2048
#define DH  64
#define KVB 64
#define BH  (NB * NH)

#define L2E 1.44269504088896f
#define QSCL (0.125f * L2E)

typedef __attribute__((ext_vector_type(8))) short bf16x8;
typedef __attribute__((ext_vector_type(4))) short bf16x4;
typedef __attribute__((ext_vector_type(4))) float f32x4;
typedef __attribute__((ext_vector_type(2))) unsigned short u16x2;

#define EXP2F(x) __builtin_amdgcn_exp2f(x)

// workspace: Kb bf16[bh][kv][d] | Vg2 bf16[bh][T=kv/64][wk][nt][l16][g][8] (PV-frag layout)
#define WS_KB   0u
#define WS_VG   6291456u
#define WS_NEED 12582912u

__device__ __forceinline__ unsigned short f2bf(float f) {
    unsigned int u = __float_as_uint(f);
    u += 0x7FFFu + ((u >> 16) & 1u);          // round-to-nearest-even
    return (unsigned short)(u >> 16);
}
__device__ __forceinline__ float bf2f(unsigned short h) {
    return __uint_as_float((unsigned int)h << 16);
}

// ============ pass 1: K -> bf16 row-major, V -> PV-fragment layout Vg2 ============
__global__ __launch_bounds__(256)
void conv_kv(const float* __restrict__ K, const float* __restrict__ V,
             unsigned short* __restrict__ Kb, unsigned short* __restrict__ Vg2)
{
    const int tid = threadIdx.x;
    const int kvt = blockIdx.x & 31;
    const int bh  = blockIdx.x >> 5;
    const int kv0 = kvt * 64;

    const float* ksrc = K + ((size_t)bh * NKV + kv0) * DH;
    const float* vsrc = V + ((size_t)bh * NKV + kv0) * DH;
    unsigned short* kdst = Kb + ((size_t)bh * NKV + kv0) * DH;
    unsigned short* vg2T = Vg2 + (size_t)bh * NKV * DH + (size_t)kvt * 4096;

    __shared__ float Ts[64][65];

    // K: row-major copy-cast
#pragma unroll
    for (int p = 0; p < 2; ++p) {
        const int ch = p * 256 + tid;
        const int row = ch >> 3, c8 = (ch & 7) * 8;
        const float4 f0 = *(const float4*)(ksrc + (size_t)row * DH + c8);
        const float4 f1 = *(const float4*)(ksrc + (size_t)row * DH + c8 + 4);
        bf16x8 o;
        o[0] = (short)f2bf(f0.x); o[1] = (short)f2bf(f0.y);
        o[2] = (short)f2bf(f0.z); o[3] = (short)f2bf(f0.w);
        o[4] = (short)f2bf(f1.x); o[5] = (short)f2bf(f1.y);
        o[6] = (short)f2bf(f1.z); o[7] = (short)f2bf(f1.w);
        *(bf16x8*)(kdst + (size_t)row * DH + c8) = o;
    }
    // V tile (rows = kv, cols = d) -> LDS
#pragma unroll
    for (int p = 0; p < 4; ++p) {
        const int fi = p * 1024 + tid * 4;
        const int row = fi >> 6, col = fi & 63;
        const float4 f = *(const float4*)(vsrc + (size_t)row * DH + col);
        Ts[row][col] = f.x; Ts[row][col + 1] = f.y;
        Ts[row][col + 2] = f.z; Ts[row][col + 3] = f.w;
    }
    __syncthreads();
    // emit Vg2: chunk ci = wk*256 + nt*64 + l16*4 + g holds 8 bf16:
    //   elem j2 -> V^T[d = nt*16+l16][kv = wk*32 + (j2>>2)*16 + g*4 + (j2&3)]
    {
        const int ci0 = tid * 2;            // thread owns chunks ci0, ci0+1 (g pair)
        const int g0  = ci0 & 3;
        const int l   = (ci0 >> 2) & 15;
        const int nt  = (ci0 >> 6) & 3;
        const int wkk = (ci0 >> 8) & 1;
        const int d   = nt * 16 + l;
        bf16x8 o2[2];
#pragma unroll
        for (int gg = 0; gg < 2; ++gg) {
            const int g = g0 + gg;
#pragma unroll
            for (int j2 = 0; j2 < 8; ++j2) {
                const int kv = wkk * 32 + ((j2 >> 2) << 4) + g * 4 + (j2 & 3);
                o2[gg][j2] = (short)f2bf(Ts[kv][d]);
            }
        }
        *(bf16x8*)(vg2T + tid * 16)     = o2[0];
        *(bf16x8*)(vg2T + tid * 16 + 8) = o2[1];
    }
}

// ============ pass 2: R18 structure, K-only LDS, V from global (L2, XCD-local) ============
// LDS arena (bytes):
//   [0,     8448)  bias2: reversed band, 2 shifted copies u16[2][2112]
//   [8448, 26880)  Ks2[2][64][72] u16     | merge: mO f32[4][64][17] + mML f32[128]
#define ARENA_BYTES 26880
#define KS_OFF 8448
#define BUF_STRIDE 9216   // 64*72*2 bytes

__global__ __launch_bounds__(512, 2)
void attn_fwd(const unsigned short* __restrict__ Kb, const unsigned short* __restrict__ Vg2,
              const float* __restrict__ Q, const float* __restrict__ M,
              const float* __restrict__ Bias, float* __restrict__ O)
{
    const int tid  = threadIdx.x;
    const int w    = tid >> 6;      // wave 0..7
    const int wq   = w >> 1;        // q-subtile: rows [wq*16, wq*16+16)
    const int wk   = w & 1;         // kv-half: cols [wk*32, wk*32+32) of each 64-tile
    const int lane = tid & 63;
    const int l16  = lane & 15;     // this lane's q row
    const int g    = lane >> 4;

    // XCD-local decode: all q-tiles of one (b,h) share an XCD (24 % 8 == 0)
    const int bh = blockIdx.x % BH;
    const int qt = blockIdx.x / BH;
    const int h  = bh % NH;
    const int b  = bh / NH;
    const int q0 = qt * 64;

    __shared__ __align__(16) char arena[ARENA_BYTES];
    unsigned short* bias2 = (unsigned short*)arena;   // [2][2112]: rev band, shifts 0/1

    // reversed bias band (bf16, pre-scaled by log2e)
    for (int x = tid; x < 2112; x += 512) {
        const unsigned short v = f2bf(L2E * Bias[(size_t)(q0 + 1 + x) * NH + h]);
        bias2[2111 - x] = v;                       // rev0
        if (x <= 2110) bias2[2112 + 2110 - x] = v; // rev1
    }

    // Q fragments pre-scaled by 0.125*log2e; B-operand of swapped QK
    const float* qptr = Q + ((size_t)bh * NQ + q0 + wq * 16 + l16) * DH;
    bf16x8 qa[2];
#pragma unroll
    for (int dc = 0; dc < 2; ++dc) {
        const float4 f0 = *(const float4*)(qptr + dc * 32 + g * 8);
        const float4 f1 = *(const float4*)(qptr + dc * 32 + g * 8 + 4);
        qa[dc][0] = (short)f2bf(f0.x * QSCL); qa[dc][1] = (short)f2bf(f0.y * QSCL);
        qa[dc][2] = (short)f2bf(f0.z * QSCL); qa[dc][3] = (short)f2bf(f0.w * QSCL);
        qa[dc][4] = (short)f2bf(f1.x * QSCL); qa[dc][5] = (short)f2bf(f1.y * QSCL);
        qa[dc][6] = (short)f2bf(f1.z * QSCL); qa[dc][7] = (short)f2bf(f1.w * QSCL);
    }

    // o[nt][reg] = O^T[d = nt*16 + g*4 + reg][q = l16]
    f32x4 o[4];
#pragma unroll
    for (int nt = 0; nt < 4; ++nt) { o[nt][0]=0.f; o[nt][1]=0.f; o[nt][2]=0.f; o[nt][3]=0.f; }
    float m_r = -1e30f;
    float l_r = 0.f;

    const unsigned short* kbB = Kb + (size_t)bh * NKV * DH;
    // per-wave V fragment pointer: tile t adds t*4096 shorts
    const unsigned short* vg2W = Vg2 + (size_t)bh * NKV * DH
                               + wk * 2048 + l16 * 32 + g * 8;
    const float* mbase = M + (size_t)b * NQ * NKV
                           + (size_t)(q0 + wq * 16 + l16) * NKV + wk * 32 + g * 4;

    const int srow = tid >> 3, sc8 = (tid & 7) * 8;
    const int ldoff = srow * 144 + sc8 * 2;

    // ---- prologue: K tile0 staged; K tile1, mask tile0, V tile0 in regs
    bf16x8 krB;
    float4 mr4[2], mrn4[2];
    bf16x8 va_c[4], va_n[4];
    krB = *(const bf16x8*)(kbB + (size_t)srow * DH + sc8);
#pragma unroll
    for (int nt = 0; nt < 2; ++nt) mr4[nt] = *(const float4*)(mbase + nt * 16);
#pragma unroll
    for (int nt = 0; nt < 4; ++nt)
        va_c[nt] = *(const bf16x8*)(vg2W + nt * 512);
    *(bf16x8*)(arena + KS_OFF + ldoff) = krB;
    krB = *(const bf16x8*)(kbB + (size_t)(64 + srow) * DH + sc8);
    __syncthreads();

    int cur = 0;
    for (int t = 0; t < NKV / KVB; ++t) {
        const int kv0 = t * KVB;
        const int tn  = ((t + 1) & (NKV / KVB - 1)) * KVB;
        const int t2  = ((t + 2) & (NKV / KVB - 1)) * KVB;
        const int nxt = cur ^ 1;

        // stage K[t+1] -> buf[nxt]; issue K[t+2]; mask[t+1]; V[t+1] (global, L2-hot)
        *(bf16x8*)(arena + KS_OFF + nxt * BUF_STRIDE + ldoff) = krB;
        krB = *(const bf16x8*)(kbB + (size_t)(t2 + srow) * DH + sc8);
#pragma unroll
        for (int nt = 0; nt < 2; ++nt) mrn4[nt] = *(const float4*)(mbase + tn + nt * 16);
#pragma unroll
        for (int nt = 0; nt < 4; ++nt)
            va_n[nt] = *(const bf16x8*)(vg2W + (size_t)(tn >> 6) * 4096 + nt * 512);

        const unsigned short (*Ks)[72] = (const unsigned short(*)[72])(arena + KS_OFF + cur * BUF_STRIDE);

        // S^T = K Q^T (log2 domain)
        f32x4 s[2];
        __builtin_amdgcn_s_setprio(1);
#pragma unroll
        for (int nt = 0; nt < 2; ++nt) {
            f32x4 acc; acc[0]=0.f; acc[1]=0.f; acc[2]=0.f; acc[3]=0.f;
            const int kvrow = wk * 32 + nt * 16 + l16;
            const bf16x8 kb0 = *(const bf16x8*)(&Ks[kvrow][g * 8]);
            const bf16x8 kb1 = *(const bf16x8*)(&Ks[kvrow][32 + g * 8]);
            acc = __builtin_amdgcn_mfma_f32_16x16x32_bf16(kb0, qa[0], acc, 0, 0, 0);
            acc = __builtin_amdgcn_mfma_f32_16x16x32_bf16(kb1, qa[1], acc, 0, 0, 0);
            s[nt] = acc;
        }
        __builtin_amdgcn_s_setprio(0);

        // bias via reversed 2-copy band + mask
        const int ib0 = (wq * 16 + l16) - (kv0 + wk * 32 + g * 4) + 2047;
#pragma unroll
        for (int nt = 0; nt < 2; ++nt) {
            const int j0 = 2111 - (ib0 - nt * 16);
            const int r  = j0 & 1;
            const unsigned short* bp = bias2 + r * 2112 + (j0 - r);
            const u16x2 b01 = *(const u16x2*)(bp);
            const u16x2 b23 = *(const u16x2*)(bp + 2);
            s[nt][0] += __fmaf_rn(nt ? mr4[1].x : mr4[0].x, L2E, bf2f(b01[0]));
            s[nt][1] += __fmaf_rn(nt ? mr4[1].y : mr4[0].y, L2E, bf2f(b01[1]));
            s[nt][2] += __fmaf_rn(nt ? mr4[1].z : mr4[0].z, L2E, bf2f(b23[0]));
            s[nt][3] += __fmaf_rn(nt ? mr4[1].w : mr4[0].w, L2E, bf2f(b23[1]));
        }

        // shuffle-free softmax
        const float x0  = fmaxf(fmaxf(s[0][0], s[0][1]), s[0][2]);
        const float x1  = fmaxf(fmaxf(s[0][3], s[1][0]), s[1][1]);
        const float x2  = fmaxf(s[1][2], s[1][3]);
        const float lmx = fmaxf(fmaxf(x0, x1), x2);
        if (__any(lmx > m_r + 8.0f)) {
            float mx = lmx;
            mx = fmaxf(mx, __shfl_xor(mx, 16));
            mx = fmaxf(mx, __shfl_xor(mx, 32));
            const float mn = fmaxf(m_r, mx);
            const float alpha = EXP2F(m_r - mn);
            m_r = mn;
            l_r *= alpha;
#pragma unroll
            for (int nt = 0; nt < 4; ++nt) {
                o[nt][0] *= alpha; o[nt][1] *= alpha;
                o[nt][2] *= alpha; o[nt][3] *= alpha;
            }
        }
        f32x4 pv[2];
#pragma unroll
        for (int nt = 0; nt < 2; ++nt) {
            pv[nt][0] = EXP2F(s[nt][0] - m_r);
            pv[nt][1] = EXP2F(s[nt][1] - m_r);
            pv[nt][2] = EXP2F(s[nt][2] - m_r);
            pv[nt][3] = EXP2F(s[nt][3] - m_r);
        }
        l_r += ((pv[0][0] + pv[0][1]) + (pv[0][2] + pv[0][3]))
             + ((pv[1][0] + pv[1][1]) + (pv[1][2] + pv[1][3]));

        mr4[0] = mrn4[0]; mr4[1] = mrn4[1];

        // P pack via v_cvt_pk_bf16_f32
        union { unsigned u[4]; bf16x8 v; } pb8;
        asm("v_cvt_pk_bf16_f32 %0, %1, %2" : "=v"(pb8.u[0]) : "v"(pv[0][0]), "v"(pv[0][1]));
        asm("v_cvt_pk_bf16_f32 %0, %1, %2" : "=v"(pb8.u[1]) : "v"(pv[0][2]), "v"(pv[0][3]));
        asm("v_cvt_pk_bf16_f32 %0, %1, %2" : "=v"(pb8.u[2]) : "v"(pv[1][0]), "v"(pv[1][1]));
        asm("v_cvt_pk_bf16_f32 %0, %1, %2" : "=v"(pb8.u[3]) : "v"(pv[1][2]), "v"(pv[1][3]));

        // PV: 4x K=32 MFMA with V from registers (loaded last iteration)
        __builtin_amdgcn_s_setprio(1);
#pragma unroll
        for (int nt = 0; nt < 4; ++nt)
            o[nt] = __builtin_amdgcn_mfma_f32_16x16x32_bf16(va_c[nt], pb8.v, o[nt], 0, 0, 0);
        __builtin_amdgcn_s_setprio(0);

        // rotate V regs
#pragma unroll
        for (int nt = 0; nt < 4; ++nt) va_c[nt] = va_n[nt];

        __syncthreads();
        cur = nxt;
    }

    // one-time cross-lane l reduce
    l_r += __shfl_xor(l_r, 16);
    l_r += __shfl_xor(l_r, 32);

    // ==== merge the two kv-halves (wk=0 <- wk=1) through LDS ====
    float (*mO)[64][17] = (float(*)[64][17])(arena + KS_OFF);       // [wq][d][q]
    float* mML          = (float*)(arena + KS_OFF + 17408);         // m[64] | l[64]

    __syncthreads();
    if (wk == 1) {
#pragma unroll
        for (int nt = 0; nt < 4; ++nt) {
#pragma unroll
            for (int reg = 0; reg < 4; ++reg)
                mO[wq][nt * 16 + g * 4 + reg][l16] = o[nt][reg];
        }
        if (g == 0) {
            mML[wq * 16 + l16]      = m_r;
            mML[64 + wq * 16 + l16] = l_r;
        }
    }
    __syncthreads();
    if (wk == 0) {
        const float m1 = mML[wq * 16 + l16];
        const float l1 = mML[64 + wq * 16 + l16];
        const float mn = fmaxf(m_r, m1);
        const float a0 = EXP2F(m_r - mn);
        const float a1 = EXP2F(m1 - mn);
        const float inv = 1.f / (l_r * a0 + l1 * a1);
        float* obase = O + ((size_t)bh * NQ + q0 + wq * 16 + l16) * DH;
#pragma unroll
        for (int nt = 0; nt < 4; ++nt) {
            float4 ov;
            ov.x = (o[nt][0] * a0 + mO[wq][nt * 16 + g * 4 + 0][l16] * a1) * inv;
            ov.y = (o[nt][1] * a0 + mO[wq][nt * 16 + g * 4 + 1][l16] * a1) * inv;
            ov.z = (o[nt][2] * a0 + mO[wq][nt * 16 + g * 4 + 2][l16] * a1) * inv;
            ov.w = (o[nt][3] * a0 + mO[wq][nt * 16 + g * 4 + 3][l16] * a1) * inv;
            *(float4*)(obase + nt * 16 + g * 4) = ov;
        }
    }
}

// ============ fallback: R2 kernel (known-good) ============
__global__ __launch_bounds__(256, 3)
void attn_full(const float* __restrict__ Q, const float* __restrict__ K,
               const float* __restrict__ V, const float* __restrict__ M,
               const float* __restrict__ Bias, float* __restrict__ O)
{
    const int tid  = threadIdx.x;
    const int wv   = tid >> 6;
    const int lane = tid & 63;
    const int l16  = lane & 15;
    const int g    = lane >> 4;

    const int qt = blockIdx.x & 31;
    const int h  = (blockIdx.x >> 5) % NH;
    const int b  = blockIdx.x / (32 * NH);
    const int q0 = qt * 64;

    __shared__ float bias_s[2112];
    __shared__ unsigned short Ks[64][72];
    __shared__ unsigned short Vs[64][72];
    __shared__ unsigned short Ps[4][16][72];

    for (int i = tid; i < 2112; i += 256)
        bias_s[i] = Bias[(size_t)(q0 + 1 + i) * NH + h];

    const float* qptr = Q + (((size_t)b * NH + h) * NQ + q0 + wv * 16 + l16) * DH;
    bf16x8 qa[2];
#pragma unroll
    for (int dc = 0; dc < 2; ++dc) {
        const float4 f0 = *(const float4*)(qptr + dc * 32 + g * 8);
        const float4 f1 = *(const float4*)(qptr + dc * 32 + g * 8 + 4);
        qa[dc][0] = (short)f2bf(f0.x); qa[dc][1] = (short)f2bf(f0.y);
        qa[dc][2] = (short)f2bf(f0.z); qa[dc][3] = (short)f2bf(f0.w);
        qa[dc][4] = (short)f2bf(f1.x); qa[dc][5] = (short)f2bf(f1.y);
        qa[dc][6] = (short)f2bf(f1.z); qa[dc][7] = (short)f2bf(f1.w);
    }

    f32x4 o[4];
#pragma unroll
    for (int nt = 0; nt < 4; ++nt) { o[nt][0]=0.f; o[nt][1]=0.f; o[nt][2]=0.f; o[nt][3]=0.f; }
    float m_r[4] = {-1e30f, -1e30f, -1e30f, -1e30f};
    float l_r[4] = {0.f, 0.f, 0.f, 0.f};

    const float* kbase = K + ((size_t)b * NH + h) * NKV * DH;
    const float* vbase = V + ((size_t)b * NH + h) * NKV * DH;
    const float* mrow[4];
#pragma unroll
    for (int r = 0; r < 4; ++r)
        mrow[r] = M + (size_t)b * NQ * NKV + (size_t)(q0 + wv * 16 + g * 4 + r) * NKV + l16;

    const int r0 = tid >> 4, c0 = (tid & 15) * 4;

    float4 kr[4], vr[4];
    float  mr[4][4];
#pragma unroll
    for (int i = 0; i < 4; ++i) {
        kr[i] = *(const float4*)(kbase + (size_t)(i * 16 + r0) * DH + c0);
        vr[i] = *(const float4*)(vbase + (size_t)(i * 16 + r0) * DH + c0);
    }
#pragma unroll
    for (int r = 0; r < 4; ++r)
#pragma unroll
        for (int nt = 0; nt < 4; ++nt) mr[r][nt] = mrow[r][nt * 16];

    for (int t = 0; t < NKV / 64; ++t) {
        const int kv0 = t * 64;
        const int kvn = ((t + 1) & 31) * 64;

        __syncthreads();
#pragma unroll
        for (int i = 0; i < 4; ++i) {
            unsigned short* dst = &Ks[i * 16 + r0][c0];
            dst[0] = f2bf(kr[i].x); dst[1] = f2bf(kr[i].y);
            dst[2] = f2bf(kr[i].z); dst[3] = f2bf(kr[i].w);
        }
#pragma unroll
        for (int i = 0; i < 4; ++i) {
            const int rr = i * 16 + r0;
            Vs[c0 + 0][rr] = f2bf(vr[i].x); Vs[c0 + 1][rr] = f2bf(vr[i].y);
            Vs[c0 + 2][rr] = f2bf(vr[i].z); Vs[c0 + 3][rr] = f2bf(vr[i].w);
        }
#pragma unroll
        for (int i = 0; i < 4; ++i) {
            kr[i] = *(const float4*)(kbase + (size_t)(kvn + i * 16 + r0) * DH + c0);
            vr[i] = *(const float4*)(vbase + (size_t)(kvn + i * 16 + r0) * DH + c0);
        }
        __syncthreads();

        f32x4 s[4];
#pragma unroll
        for (int nt = 0; nt < 4; ++nt) {
            f32x4 acc; acc[0]=0.f; acc[1]=0.f; acc[2]=0.f; acc[3]=0.f;
            const bf16x8 kb0 = *(const bf16x8*)(&Ks[nt * 16 + l16][g * 8]);
            const bf16x8 kb1 = *(const bf16x8*)(&Ks[nt * 16 + l16][32 + g * 8]);
            acc = __builtin_amdgcn_mfma_f32_16x16x32_bf16(qa[0], kb0, acc, 0, 0, 0);
            acc = __builtin_amdgcn_mfma_f32_16x16x32_bf16(qa[1], kb1, acc, 0, 0, 0);
            s[nt] = acc;
        }

#pragma unroll
        for (int r = 0; r < 4; ++r) {
            const int qr = wv * 16 + g * 4 + r;
#pragma unroll
            for (int nt = 0; nt < 4; ++nt) {
                float x = s[nt][r] * 0.125f + mr[r][nt];
                x += bias_s[qr - (kv0 + nt * 16 + l16) + 2047];
                s[nt][r] = x;
            }
            float mx = fmaxf(fmaxf(s[0][r], s[1][r]), fmaxf(s[2][r], s[3][r]));
            mx = fmaxf(mx, __shfl_xor(mx, 1));
            mx = fmaxf(mx, __shfl_xor(mx, 2));
            mx = fmaxf(mx, __shfl_xor(mx, 4));
            mx = fmaxf(mx, __shfl_xor(mx, 8));
            const float mo = m_r[r];
            const float mn = fmaxf(mo, mx);
            m_r[r] = mn;
            const float alpha = __expf(mo - mn);
            float p[4], rs = 0.f;
#pragma unroll
            for (int nt = 0; nt < 4; ++nt) { p[nt] = __expf(s[nt][r] - mn); rs += p[nt]; }
            rs += __shfl_xor(rs, 1);
            rs += __shfl_xor(rs, 2);
            rs += __shfl_xor(rs, 4);
            rs += __shfl_xor(rs, 8);
            l_r[r] = l_r[r] * alpha + rs;
#pragma unroll
            for (int nt = 0; nt < 4; ++nt) o[nt][r] *= alpha;
#pragma unroll
            for (int nt = 0; nt < 4; ++nt)
                Ps[wv][g * 4 + r][nt * 16 + l16] = f2bf(p[nt]);
        }

#pragma unroll
        for (int r = 0; r < 4; ++r)
#pragma unroll
            for (int nt = 0; nt < 4; ++nt) mr[r][nt] = mrow[r][kvn + nt * 16];

#pragma unroll
        for (int kc = 0; kc < 2; ++kc) {
            const bf16x8 pa = *(const bf16x8*)(&Ps[wv][l16][kc * 32 + g * 8]);
#pragma unroll
            for (int nt = 0; nt < 4; ++nt) {
                const bf16x8 vb = *(const bf16x8*)(&Vs[nt * 16 + l16][kc * 32 + g * 8]);
                o[nt] = __builtin_amdgcn_mfma_f32_16x16x32_bf16(pa, vb, o[nt], 0, 0, 0);
            }
        }
    }

    float* obase = O + (((size_t)b * NH + h) * NQ + q0 + wv * 16) * DH;
#pragma unroll
    for (int r = 0; r < 4; ++r) {
        const float inv = 1.f / l_r[r];
#pragma unroll
        for (int nt = 0; nt < 4; ++nt)
            obase[(size_t)(g * 4 + r) * DH + nt * 16 + l16] = o[nt][r] * inv;
    }
}

extern "C" void kernel_launch(void* const* d_in, const int* in_sizes, int n_in,
                              void* d_out, int out_size, void* d_ws, size_t ws_size,
                              hipStream_t stream) {
    const float* Q    = (const float*)d_in[0];
    const float* K    = (const float*)d_in[1];
    const float* V    = (const float*)d_in[2];
    const float* M    = (const float*)d_in[3];
    const float* Bias = (const float*)d_in[4];
    float* O = (float*)d_out;

    if (ws_size >= (size_t)WS_NEED) {
        unsigned short* Kb  = (unsigned short*)((char*)d_ws + WS_KB);
        unsigned short* Vg2 = (unsigned short*)((char*)d_ws + WS_VG);
        conv_kv<<<dim3(BH * 32), dim3(256), 0, stream>>>(K, V, Kb, Vg2);
        attn_fwd<<<dim3(BH * 32), dim3(512), 0, stream>>>(Kb, Vg2, Q, M, Bias, O);
    } else {
        attn_full<<<dim3(BH * 32), dim3(256), 0, stream>>>(Q, K, V, M, Bias, O);
    }
}

// Round 22
// 78.302 us; speedup vs baseline: 1.4338x; 1.4338x over previous
//
#include <hip/hip_runtime.h>

#define NB  2
#define NH  12
#define NQ  2048
#define NKV 2048
#define DH  64
#define KVB 64
#define BH  (NB * NH)

#define L2E 1.44269504088896f
#define QSCL (0.125f * L2E)

typedef __attribute__((ext_vector_type(8))) short bf16x8;
typedef __attribute__((ext_vector_type(4))) short bf16x4;
typedef __attribute__((ext_vector_type(4))) float f32x4;
typedef __attribute__((ext_vector_type(2))) unsigned short u16x2;

#define EXP2F(x) __builtin_amdgcn_exp2f(x)

// workspace: Kb bf16[bh][kv][d] | Vt bf16[bh][d][kv] (cols permuted within 64-blocks)
#define WS_KB   0u
#define WS_VT   6291456u
#define WS_NEED 12582912u

__device__ __forceinline__ unsigned short f2bf(float f) {
    unsigned int u = __float_as_uint(f);
    u += 0x7FFFu + ((u >> 16) & 1u);          // round-to-nearest-even
    return (unsigned short)(u >> 16);
}
__device__ __forceinline__ float bf2f(unsigned short h) {
    return __uint_as_float((unsigned int)h << 16);
}
// within-64 kv permutation: k6 = wk*32 + c*16 + g*4 + j  ->  wk*32 + g*8 + c*4 + j
__device__ __forceinline__ int permk6(int k6) {
    return (k6 & 32) + ((k6 & 12) << 1) + ((k6 & 16) >> 2) + (k6 & 3);
}

// ============ pass 1: K -> bf16 row-major, V -> bf16 transpose with permuted cols ======
__global__ __launch_bounds__(256)
void conv_kv(const float* __restrict__ K, const float* __restrict__ V,
             unsigned short* __restrict__ Kb, unsigned short* __restrict__ Vt)
{
    const int tid = threadIdx.x;
    const int kvt = blockIdx.x & 31;
    const int bh  = blockIdx.x >> 5;
    const int kv0 = kvt * 64;

    const float* ksrc = K + ((size_t)bh * NKV + kv0) * DH;
    const float* vsrc = V + ((size_t)bh * NKV + kv0) * DH;
    unsigned short* kdst = Kb + ((size_t)bh * NKV + kv0) * DH;
    unsigned short* vdst = Vt + (size_t)bh * DH * NKV + kv0;

    __shared__ float Ts[64][65];

#pragma unroll
    for (int p = 0; p < 2; ++p) {
        const int ch = p * 256 + tid;
        const int row = ch >> 3, c8 = (ch & 7) * 8;
        const float4 f0 = *(const float4*)(ksrc + (size_t)row * DH + c8);
        const float4 f1 = *(const float4*)(ksrc + (size_t)row * DH + c8 + 4);
        bf16x8 o;
        o[0] = (short)f2bf(f0.x); o[1] = (short)f2bf(f0.y);
        o[2] = (short)f2bf(f0.z); o[3] = (short)f2bf(f0.w);
        o[4] = (short)f2bf(f1.x); o[5] = (short)f2bf(f1.y);
        o[6] = (short)f2bf(f1.z); o[7] = (short)f2bf(f1.w);
        *(bf16x8*)(kdst + (size_t)row * DH + c8) = o;
    }
#pragma unroll
    for (int p = 0; p < 4; ++p) {
        const int fi = p * 1024 + tid * 4;
        const int row = fi >> 6, col = fi & 63;
        const float4 f = *(const float4*)(vsrc + (size_t)row * DH + col);
        Ts[row][col] = f.x; Ts[row][col + 1] = f.y;
        Ts[row][col + 2] = f.z; Ts[row][col + 3] = f.w;
    }
    __syncthreads();
#pragma unroll
    for (int p = 0; p < 2; ++p) {
        const int ch = p * 256 + tid;
        const int d = ch >> 3, c8 = (ch & 7) * 8;   // kv chunk within 64-block
        bf16x8 o;
#pragma unroll
        for (int j = 0; j < 8; ++j) o[j] = (short)f2bf(Ts[c8 + j][d]);
        unsigned short* vrow = vdst + (size_t)d * NKV;
        *(uint2*)(vrow + permk6(c8))     = ((const uint2*)&o)[0];
        *(uint2*)(vrow + permk6(c8 + 4)) = ((const uint2*)&o)[1];
    }
}

// ============ pass 2: R18 final — K/V LDS-staged, shuffle-free softmax, K=32 PV ========
// LDS arena (bytes):
//   [0,     8448)  bias2: reversed band, 2 shifted copies u16[2][2112]
//   [8448, 26880)  Ks2[2][64][72] u16     | merge: mO f32[4][64][17] + mML f32[128]
//   [26880,45312)  Vs2[2][64][72] u16  (permuted cols)
#define ARENA_BYTES 45312
#define KS_OFF 8448
#define VS_OFF 26880
#define BUF_STRIDE 9216   // 64*72*2 bytes

__global__ __launch_bounds__(512, 2)
void attn_fwd(const unsigned short* __restrict__ Kb, const unsigned short* __restrict__ Vt,
              const float* __restrict__ Q, const float* __restrict__ M,
              const float* __restrict__ Bias, float* __restrict__ O)
{
    const int tid  = threadIdx.x;
    const int w    = tid >> 6;      // wave 0..7
    const int wq   = w >> 1;        // q-subtile: rows [wq*16, wq*16+16)
    const int wk   = w & 1;         // kv-half: cols [wk*32, wk*32+32) of each 64-tile
    const int lane = tid & 63;
    const int l16  = lane & 15;     // this lane's q row
    const int g    = lane >> 4;

    const int qt = blockIdx.x & 31;
    const int bh = blockIdx.x >> 5;
    const int h  = bh % NH;
    const int b  = bh / NH;
    const int q0 = qt * 64;

    __shared__ __align__(16) char arena[ARENA_BYTES];
    unsigned short* bias2 = (unsigned short*)arena;   // [2][2112]: rev band, shifts 0/1

    // reversed bias band (bf16, pre-scaled by log2e)
    for (int x = tid; x < 2112; x += 512) {
        const unsigned short v = f2bf(L2E * Bias[(size_t)(q0 + 1 + x) * NH + h]);
        bias2[2111 - x] = v;                       // rev0
        if (x <= 2110) bias2[2112 + 2110 - x] = v; // rev1
    }

    // Q fragments pre-scaled by 0.125*log2e; B-operand of swapped QK
    const float* qptr = Q + ((size_t)bh * NQ + q0 + wq * 16 + l16) * DH;
    bf16x8 qa[2];
#pragma unroll
    for (int dc = 0; dc < 2; ++dc) {
        const float4 f0 = *(const float4*)(qptr + dc * 32 + g * 8);
        const float4 f1 = *(const float4*)(qptr + dc * 32 + g * 8 + 4);
        qa[dc][0] = (short)f2bf(f0.x * QSCL); qa[dc][1] = (short)f2bf(f0.y * QSCL);
        qa[dc][2] = (short)f2bf(f0.z * QSCL); qa[dc][3] = (short)f2bf(f0.w * QSCL);
        qa[dc][4] = (short)f2bf(f1.x * QSCL); qa[dc][5] = (short)f2bf(f1.y * QSCL);
        qa[dc][6] = (short)f2bf(f1.z * QSCL); qa[dc][7] = (short)f2bf(f1.w * QSCL);
    }

    // o[nt][reg] = O^T[d = nt*16 + g*4 + reg][q = l16]
    f32x4 o[4];
#pragma unroll
    for (int nt = 0; nt < 4; ++nt) { o[nt][0]=0.f; o[nt][1]=0.f; o[nt][2]=0.f; o[nt][3]=0.f; }
    float m_r = -1e30f;   // wave-uniform running max (log2 domain)
    float l_r = 0.f;      // per-lane partial sum (reduced once in epilogue)

    const unsigned short* kbB = Kb + (size_t)bh * NKV * DH;
    const unsigned short* vtB = Vt + (size_t)bh * DH * NKV;
    const float* mbase = M + (size_t)b * NQ * NKV
                           + (size_t)(q0 + wq * 16 + l16) * NKV + wk * 32 + g * 4;

    const int srow = tid >> 3, sc8 = (tid & 7) * 8;
    const int ldoff = srow * 144 + sc8 * 2;

    // ---- prologue
    bf16x8 krB, vrB;
    float4 mr4[2], mrn4[2];
    krB = *(const bf16x8*)(kbB + (size_t)srow * DH + sc8);
    vrB = *(const bf16x8*)(vtB + (size_t)srow * NKV + sc8);
#pragma unroll
    for (int nt = 0; nt < 2; ++nt) mr4[nt] = *(const float4*)(mbase + nt * 16);

    *(bf16x8*)(arena + KS_OFF + ldoff) = krB;
    *(bf16x8*)(arena + VS_OFF + ldoff) = vrB;
    krB = *(const bf16x8*)(kbB + (size_t)(64 + srow) * DH + sc8);
    vrB = *(const bf16x8*)(vtB + (size_t)srow * NKV + 64 + sc8);
    __syncthreads();

    int cur = 0;
    for (int t = 0; t < NKV / KVB; ++t) {
        const int kv0 = t * KVB;
        const int tn  = ((t + 1) & (NKV / KVB - 1)) * KVB;
        const int t2  = ((t + 2) & (NKV / KVB - 1)) * KVB;
        const int nxt = cur ^ 1;

        *(bf16x8*)(arena + KS_OFF + nxt * BUF_STRIDE + ldoff) = krB;
        *(bf16x8*)(arena + VS_OFF + nxt * BUF_STRIDE + ldoff) = vrB;
        krB = *(const bf16x8*)(kbB + (size_t)(t2 + srow) * DH + sc8);
        vrB = *(const bf16x8*)(vtB + (size_t)srow * NKV + t2 + sc8);
#pragma unroll
        for (int nt = 0; nt < 2; ++nt) mrn4[nt] = *(const float4*)(mbase + tn + nt * 16);

        const unsigned short (*Ks)[72] = (const unsigned short(*)[72])(arena + KS_OFF + cur * BUF_STRIDE);
        const unsigned short (*Vs)[72] = (const unsigned short(*)[72])(arena + VS_OFF + cur * BUF_STRIDE);

        // S^T = K Q^T (log2 domain): s[nt][reg] = S[kv = wk*32+nt*16+g*4+reg][q = l16]
        f32x4 s[2];
#pragma unroll
        for (int nt = 0; nt < 2; ++nt) {
            f32x4 acc; acc[0]=0.f; acc[1]=0.f; acc[2]=0.f; acc[3]=0.f;
            const int kvrow = wk * 32 + nt * 16 + l16;
            const bf16x8 kb0 = *(const bf16x8*)(&Ks[kvrow][g * 8]);
            const bf16x8 kb1 = *(const bf16x8*)(&Ks[kvrow][32 + g * 8]);
            acc = __builtin_amdgcn_mfma_f32_16x16x32_bf16(kb0, qa[0], acc, 0, 0, 0);
            acc = __builtin_amdgcn_mfma_f32_16x16x32_bf16(kb1, qa[1], acc, 0, 0, 0);
            s[nt] = acc;
        }

        // V fragments: one b128 per nt (permuted layout = K=32 A-frag)
        bf16x8 va2[4];
#pragma unroll
        for (int nt = 0; nt < 4; ++nt)
            va2[nt] = *(const bf16x8*)(&Vs[nt * 16 + l16][wk * 32 + g * 8]);

        // bias via reversed 2-copy band + mask
        const int ib0 = (wq * 16 + l16) - (kv0 + wk * 32 + g * 4) + 2047;
#pragma unroll
        for (int nt = 0; nt < 2; ++nt) {
            const int j0 = 2111 - (ib0 - nt * 16);
            const int r  = j0 & 1;
            const unsigned short* bp = bias2 + r * 2112 + (j0 - r);
            const u16x2 b01 = *(const u16x2*)(bp);
            const u16x2 b23 = *(const u16x2*)(bp + 2);
            s[nt][0] += __fmaf_rn(nt ? mr4[1].x : mr4[0].x, L2E, bf2f(b01[0]));
            s[nt][1] += __fmaf_rn(nt ? mr4[1].y : mr4[0].y, L2E, bf2f(b01[1]));
            s[nt][2] += __fmaf_rn(nt ? mr4[1].z : mr4[0].z, L2E, bf2f(b23[0]));
            s[nt][3] += __fmaf_rn(nt ? mr4[1].w : mr4[0].w, L2E, bf2f(b23[1]));
        }

        // shuffle-free softmax; max tree shaped for v_max3 fusion
        const float x0  = fmaxf(fmaxf(s[0][0], s[0][1]), s[0][2]);
        const float x1  = fmaxf(fmaxf(s[0][3], s[1][0]), s[1][1]);
        const float x2  = fmaxf(s[1][2], s[1][3]);
        const float lmx = fmaxf(fmaxf(x0, x1), x2);
        if (__any(lmx > m_r + 8.0f)) {
            float mx = lmx;
            mx = fmaxf(mx, __shfl_xor(mx, 16));
            mx = fmaxf(mx, __shfl_xor(mx, 32));
            const float mn = fmaxf(m_r, mx);
            const float alpha = EXP2F(m_r - mn);
            m_r = mn;
            l_r *= alpha;
#pragma unroll
            for (int nt = 0; nt < 4; ++nt) {
                o[nt][0] *= alpha; o[nt][1] *= alpha;
                o[nt][2] *= alpha; o[nt][3] *= alpha;
            }
        }
        f32x4 pv[2];
#pragma unroll
        for (int nt = 0; nt < 2; ++nt) {
            pv[nt][0] = EXP2F(s[nt][0] - m_r);
            pv[nt][1] = EXP2F(s[nt][1] - m_r);
            pv[nt][2] = EXP2F(s[nt][2] - m_r);
            pv[nt][3] = EXP2F(s[nt][3] - m_r);
        }
        l_r += ((pv[0][0] + pv[0][1]) + (pv[0][2] + pv[0][3]))
             + ((pv[1][0] + pv[1][1]) + (pv[1][2] + pv[1][3]));

        // rotate mask regs
        mr4[0] = mrn4[0]; mr4[1] = mrn4[1];

        // P pack via v_cvt_pk_bf16_f32 (4 instrs) -> bf16x8 B-frag for K=32 PV
        union { unsigned u[4]; bf16x8 v; } pb8;
        asm("v_cvt_pk_bf16_f32 %0, %1, %2" : "=v"(pb8.u[0]) : "v"(pv[0][0]), "v"(pv[0][1]));
        asm("v_cvt_pk_bf16_f32 %0, %1, %2" : "=v"(pb8.u[1]) : "v"(pv[0][2]), "v"(pv[0][3]));
        asm("v_cvt_pk_bf16_f32 %0, %1, %2" : "=v"(pb8.u[2]) : "v"(pv[1][0]), "v"(pv[1][1]));
        asm("v_cvt_pk_bf16_f32 %0, %1, %2" : "=v"(pb8.u[3]) : "v"(pv[1][2]), "v"(pv[1][3]));

        // PV: 4x K=32 MFMA — permuted V layout makes va2/pb8 matching fragments
#pragma unroll
        for (int nt = 0; nt < 4; ++nt)
            o[nt] = __builtin_amdgcn_mfma_f32_16x16x32_bf16(va2[nt], pb8.v, o[nt], 0, 0, 0);

        __syncthreads();
        cur = nxt;
    }

    // one-time cross-lane l reduce
    l_r += __shfl_xor(l_r, 16);
    l_r += __shfl_xor(l_r, 32);

    // ==== merge the two kv-halves (wk=0 <- wk=1) through LDS ====
    float (*mO)[64][17] = (float(*)[64][17])(arena + KS_OFF);       // [wq][d][q]
    float* mML          = (float*)(arena + KS_OFF + 17408);         // m[64] | l[64]

    __syncthreads();
    if (wk == 1) {
#pragma unroll
        for (int nt = 0; nt < 4; ++nt) {
#pragma unroll
            for (int reg = 0; reg < 4; ++reg)
                mO[wq][nt * 16 + g * 4 + reg][l16] = o[nt][reg];
        }
        if (g == 0) {
            mML[wq * 16 + l16]      = m_r;
            mML[64 + wq * 16 + l16] = l_r;
        }
    }
    __syncthreads();
    if (wk == 0) {
        const float m1 = mML[wq * 16 + l16];
        const float l1 = mML[64 + wq * 16 + l16];
        const float mn = fmaxf(m_r, m1);
        const float a0 = EXP2F(m_r - mn);
        const float a1 = EXP2F(m1 - mn);
        const float inv = 1.f / (l_r * a0 + l1 * a1);
        float* obase = O + ((size_t)bh * NQ + q0 + wq * 16 + l16) * DH;
#pragma unroll
        for (int nt = 0; nt < 4; ++nt) {
            float4 ov;
            ov.x = (o[nt][0] * a0 + mO[wq][nt * 16 + g * 4 + 0][l16] * a1) * inv;
            ov.y = (o[nt][1] * a0 + mO[wq][nt * 16 + g * 4 + 1][l16] * a1) * inv;
            ov.z = (o[nt][2] * a0 + mO[wq][nt * 16 + g * 4 + 2][l16] * a1) * inv;
            ov.w = (o[nt][3] * a0 + mO[wq][nt * 16 + g * 4 + 3][l16] * a1) * inv;
            *(float4*)(obase + nt * 16 + g * 4) = ov;
        }
    }
}

// ============ fallback: R2 kernel (known-good) ============
__global__ __launch_bounds__(256, 3)
void attn_full(const float* __restrict__ Q, const float* __restrict__ K,
               const float* __restrict__ V, const float* __restrict__ M,
               const float* __restrict__ Bias, float* __restrict__ O)
{
    const int tid  = threadIdx.x;
    const int wv   = tid >> 6;
    const int lane = tid & 63;
    const int l16  = lane & 15;
    const int g    = lane >> 4;

    const int qt = blockIdx.x & 31;
    const int h  = (blockIdx.x >> 5) % NH;
    const int b  = blockIdx.x / (32 * NH);
    const int q0 = qt * 64;

    __shared__ float bias_s[2112];
    __shared__ unsigned short Ks[64][72];
    __shared__ unsigned short Vs[64][72];
    __shared__ unsigned short Ps[4][16][72];

    for (int i = tid; i < 2112; i += 256)
        bias_s[i] = Bias[(size_t)(q0 + 1 + i) * NH + h];

    const float* qptr = Q + (((size_t)b * NH + h) * NQ + q0 + wv * 16 + l16) * DH;
    bf16x8 qa[2];
#pragma unroll
    for (int dc = 0; dc < 2; ++dc) {
        const float4 f0 = *(const float4*)(qptr + dc * 32 + g * 8);
        const float4 f1 = *(const float4*)(qptr + dc * 32 + g * 8 + 4);
        qa[dc][0] = (short)f2bf(f0.x); qa[dc][1] = (short)f2bf(f0.y);
        qa[dc][2] = (short)f2bf(f0.z); qa[dc][3] = (short)f2bf(f0.w);
        qa[dc][4] = (short)f2bf(f1.x); qa[dc][5] = (short)f2bf(f1.y);
        qa[dc][6] = (short)f2bf(f1.z); qa[dc][7] = (short)f2bf(f1.w);
    }

    f32x4 o[4];
#pragma unroll
    for (int nt = 0; nt < 4; ++nt) { o[nt][0]=0.f; o[nt][1]=0.f; o[nt][2]=0.f; o[nt][3]=0.f; }
    float m_r[4] = {-1e30f, -1e30f, -1e30f, -1e30f};
    float l_r[4] = {0.f, 0.f, 0.f, 0.f};

    const float* kbase = K + ((size_t)b * NH + h) * NKV * DH;
    const float* vbase = V + ((size_t)b * NH + h) * NKV * DH;
    const float* mrow[4];
#pragma unroll
    for (int r = 0; r < 4; ++r)
        mrow[r] = M + (size_t)b * NQ * NKV + (size_t)(q0 + wv * 16 + g * 4 + r) * NKV + l16;

    const int r0 = tid >> 4, c0 = (tid & 15) * 4;

    float4 kr[4], vr[4];
    float  mr[4][4];
#pragma unroll
    for (int i = 0; i < 4; ++i) {
        kr[i] = *(const float4*)(kbase + (size_t)(i * 16 + r0) * DH + c0);
        vr[i] = *(const float4*)(vbase + (size_t)(i * 16 + r0) * DH + c0);
    }
#pragma unroll
    for (int r = 0; r < 4; ++r)
#pragma unroll
        for (int nt = 0; nt < 4; ++nt) mr[r][nt] = mrow[r][nt * 16];

    for (int t = 0; t < NKV / 64; ++t) {
        const int kv0 = t * 64;
        const int kvn = ((t + 1) & 31) * 64;

        __syncthreads();
#pragma unroll
        for (int i = 0; i < 4; ++i) {
            unsigned short* dst = &Ks[i * 16 + r0][c0];
            dst[0] = f2bf(kr[i].x); dst[1] = f2bf(kr[i].y);
            dst[2] = f2bf(kr[i].z); dst[3] = f2bf(kr[i].w);
        }
#pragma unroll
        for (int i = 0; i < 4; ++i) {
            const int rr = i * 16 + r0;
            Vs[c0 + 0][rr] = f2bf(vr[i].x); Vs[c0 + 1][rr] = f2bf(vr[i].y);
            Vs[c0 + 2][rr] = f2bf(vr[i].z); Vs[c0 + 3][rr] = f2bf(vr[i].w);
        }
#pragma unroll
        for (int i = 0; i < 4; ++i) {
            kr[i] = *(const float4*)(kbase + (size_t)(kvn + i * 16 + r0) * DH + c0);
            vr[i] = *(const float4*)(vbase + (size_t)(kvn + i * 16 + r0) * DH + c0);
        }
        __syncthreads();

        f32x4 s[4];
#pragma unroll
        for (int nt = 0; nt < 4; ++nt) {
            f32x4 acc; acc[0]=0.f; acc[1]=0.f; acc[2]=0.f; acc[3]=0.f;
            const bf16x8 kb0 = *(const bf16x8*)(&Ks[nt * 16 + l16][g * 8]);
            const bf16x8 kb1 = *(const bf16x8*)(&Ks[nt * 16 + l16][32 + g * 8]);
            acc = __builtin_amdgcn_mfma_f32_16x16x32_bf16(qa[0], kb0, acc, 0, 0, 0);
            acc = __builtin_amdgcn_mfma_f32_16x16x32_bf16(qa[1], kb1, acc, 0, 0, 0);
            s[nt] = acc;
        }

#pragma unroll
        for (int r = 0; r < 4; ++r) {
            const int qr = wv * 16 + g * 4 + r;
#pragma unroll
            for (int nt = 0; nt < 4; ++nt) {
                float x = s[nt][r] * 0.125f + mr[r][nt];
                x += bias_s[qr - (kv0 + nt * 16 + l16) + 2047];
                s[nt][r] = x;
            }
            float mx = fmaxf(fmaxf(s[0][r], s[1][r]), fmaxf(s[2][r], s[3][r]));
            mx = fmaxf(mx, __shfl_xor(mx, 1));
            mx = fmaxf(mx, __shfl_xor(mx, 2));
            mx = fmaxf(mx, __shfl_xor(mx, 4));
            mx = fmaxf(mx, __shfl_xor(mx, 8));
            const float mo = m_r[r];
            const float mn = fmaxf(mo, mx);
            m_r[r] = mn;
            const float alpha = __expf(mo - mn);
            float p[4], rs = 0.f;
#pragma unroll
            for (int nt = 0; nt < 4; ++nt) { p[nt] = __expf(s[nt][r] - mn); rs += p[nt]; }
            rs += __shfl_xor(rs, 1);
            rs += __shfl_xor(rs, 2);
            rs += __shfl_xor(rs, 4);
            rs += __shfl_xor(rs, 8);
            l_r[r] = l_r[r] * alpha + rs;
#pragma unroll
            for (int nt = 0; nt < 4; ++nt) o[nt][r] *= alpha;
#pragma unroll
            for (int nt = 0; nt < 4; ++nt)
                Ps[wv][g * 4 + r][nt * 16 + l16] = f2bf(p[nt]);
        }

#pragma unroll
        for (int r = 0; r < 4; ++r)
#pragma unroll
            for (int nt = 0; nt < 4; ++nt) mr[r][nt] = mrow[r][kvn + nt * 16];

#pragma unroll
        for (int kc = 0; kc < 2; ++kc) {
            const bf16x8 pa = *(const bf16x8*)(&Ps[wv][l16][kc * 32 + g * 8]);
#pragma unroll
            for (int nt = 0; nt < 4; ++nt) {
                const bf16x8 vb = *(const bf16x8*)(&Vs[nt * 16 + l16][kc * 32 + g * 8]);
                o[nt] = __builtin_amdgcn_mfma_f32_16x16x32_bf16(pa, vb, o[nt], 0, 0, 0);
            }
        }
    }

    float* obase = O + (((size_t)b * NH + h) * NQ + q0 + wv * 16) * DH;
#pragma unroll
    for (int r = 0; r < 4; ++r) {
        const float inv = 1.f / l_r[r];
#pragma unroll
        for (int nt = 0; nt < 4; ++nt)
            obase[(size_t)(g * 4 + r) * DH + nt * 16 + l16] = o[nt][r] * inv;
    }
}

extern "C" void kernel_launch(void* const* d_in, const int* in_sizes, int n_in,
                              void* d_out, int out_size, void* d_ws, size_t ws_size,
                              hipStream_t stream) {
    const float* Q    = (const float*)d_in[0];
    const float* K    = (const float*)d_in[1];
    const float* V    = (const float*)d_in[2];
    const float* M    = (const float*)d_in[3];
    const float* Bias = (const float*)d_in[4];
    float* O = (float*)d_out;

    if (ws_size >= (size_t)WS_NEED) {
        unsigned short* Kb = (unsigned short*)((char*)d_ws + WS_KB);
        unsigned short* Vt = (unsigned short*)((char*)d_ws + WS_VT);
        conv_kv<<<dim3(BH * 32), dim3(256), 0, stream>>>(K, V, Kb, Vt);
        attn_fwd<<<dim3(BH * 32), dim3(512), 0, stream>>>(Kb, Vt, Q, M, Bias, O);
    } else {
        attn_full<<<dim3(BH * 32), dim3(256), 0, stream>>>(Q, K, V, M, Bias, O);
    }
}